// Round 9
// baseline (117.493 us; speedup 1.0000x reference)
//
#include <hip/hip_runtime.h>

#define BATCH   32
#define DIM     128
#define NBASES  8
#define SSTEPS  128
#define LDA     136   // padded row (shorts): 272 B stride, 16B-aligned rows

typedef __attribute__((ext_vector_type(8)))  short s8v;   // 8 bf16 (4 VGPR)
typedef __attribute__((ext_vector_type(4)))  short s4v;   // 4 bf16 (8B packed store)
typedef __attribute__((ext_vector_type(4)))  float f4v;   // 16x16 MFMA acc
typedef __attribute__((ext_vector_type(16))) float f16v;  // 32x32 MFMA acc

__device__ __forceinline__ f4v mf(s8v a, s8v b, f4v c) {
    return __builtin_amdgcn_mfma_f32_16x16x32_bf16(a, b, c, 0, 0, 0);
}
__device__ __forceinline__ f16v mf32(s8v a, s8v b, f16v c) {
    return __builtin_amdgcn_mfma_f32_32x32x16_bf16(a, b, c, 0, 0, 0);
}
__device__ __forceinline__ s8v ld8(const short* p) {
    return *reinterpret_cast<const s8v*>(p);
}
__device__ __forceinline__ s4v ld4(const short* p) {
    return *reinterpret_cast<const s4v*>(p);
}
__device__ __forceinline__ void st4(short* p, s4v v) {
    *reinterpret_cast<s4v*>(p) = v;   // 8B-aligned at all call sites -> ds_write_b64
}
__device__ __forceinline__ float upbf(short h) {
    return __uint_as_float(((unsigned)(unsigned short)h) << 16);
}
// split fp32 -> bf16 hi + bf16 lo (truncation; dropped residual ~2^-16 rel)
__device__ __forceinline__ void splitbf(float v, short& hi, short& lo) {
    const unsigned u = __float_as_uint(v);
    hi = (short)(u >> 16);
    const float fh = __uint_as_float(u & 0xffff0000u);
    lo = (short)(__float_as_uint(v - fh) >> 16);
}

__device__ __forceinline__ void write_out(float* __restrict__ outF, int b, int sidx,
                                          int o, int c, float val,
                                          int interleaved, int out_size)
{
    if (interleaved) {
        const int oi = ((b * SSTEPS + sidx) * DIM + o) * 2 + c;
        if (oi < out_size) outF[oi] = val;
    } else if (c == 0) {
        const int oi = (b * SSTEPS + sidx) * DIM + o;
        if (oi < out_size) outF[oi] = val;
    }
}

// ---- full 128x128x128 split-bf16 MFMA matmul: 16 waves, wave = one 32x32
// v_mfma_f32_32x32x16_bf16 tile. A row-major from "norm" planes, B^T from
// "trans" planes. TRO: acc = C tile. NMO: acct = C^T tile (operand swap on
// the SAME loaded fragments -> no extra LDS reads).
template<bool TRO, bool NMO>
__device__ __forceinline__ void mm32(const short* __restrict__ Ah,
                                     const short* __restrict__ Al,
                                     const short* __restrict__ Bh,
                                     const short* __restrict__ Bl,
                                     f16v& acc, f16v& acct,
                                     int mb, int nb, int lane)
{
    const int l31 = lane & 31, koc = (lane >> 5) * 8;
    #pragma unroll
    for (int ks = 0; ks < 8; ++ks) {
        const int ko = ks * 16 + koc;
        const s8v ah = ld8(Ah + (mb + l31) * LDA + ko);
        const s8v al = ld8(Al + (mb + l31) * LDA + ko);
        const s8v bh = ld8(Bh + (nb + l31) * LDA + ko);
        const s8v bl = ld8(Bl + (nb + l31) * LDA + ko);
        if (TRO) {
            acc = mf32(ah, bh, acc);
            acc = mf32(ah, bl, acc);
            acc = mf32(al, bh, acc);
        }
        if (NMO) {
            acct = mf32(bh, ah, acct);
            acct = mf32(bl, ah, acct);
            acct = mf32(bh, al, acct);
        }
    }
}

// ======== prologue: K_sum / K_sum^T / R_sum^T on 256 blocks -> d_ws ========
// ws layout (fp32): Ks[32][128][128], KsT[32][128][128], RsT[32][128][128] = 6 MB
__global__ __launch_bounds__(256)
void sum_kr(const float* __restrict__ kco, const float* __restrict__ rco,
            const float* __restrict__ KB,  const float* __restrict__ RB,
            float* __restrict__ ws)
{
    const int b = blockIdx.x >> 3, s = blockIdx.x & 7, t = threadIdx.x;
    const int boff = s * 16 * DIM + t * 8;           // row r, cols c..c+7
    const int r = s * 16 + (t >> 4), c = (t & 15) * 8;
    float kc[NBASES], rc[NBASES];
    #pragma unroll
    for (int n = 0; n < NBASES; ++n) {
        kc[n] = kco[b * NBASES + n];
        rc[n] = rco[b * NBASES + n];
    }
    float4 ka = {0.f,0.f,0.f,0.f}, kb4 = {0.f,0.f,0.f,0.f};
    float4 ra = {0.f,0.f,0.f,0.f}, rb4 = {0.f,0.f,0.f,0.f};
    #pragma unroll
    for (int n = 0; n < NBASES; ++n) {
        const float4 k0 = *reinterpret_cast<const float4*>(KB + n * DIM * DIM + boff);
        const float4 k1 = *reinterpret_cast<const float4*>(KB + n * DIM * DIM + boff + 4);
        const float4 r0 = *reinterpret_cast<const float4*>(RB + n * DIM * DIM + boff);
        const float4 r1 = *reinterpret_cast<const float4*>(RB + n * DIM * DIM + boff + 4);
        ka.x += kc[n] * k0.x; ka.y += kc[n] * k0.y; ka.z += kc[n] * k0.z; ka.w += kc[n] * k0.w;
        kb4.x += kc[n] * k1.x; kb4.y += kc[n] * k1.y; kb4.z += kc[n] * k1.z; kb4.w += kc[n] * k1.w;
        ra.x += rc[n] * r0.x; ra.y += rc[n] * r0.y; ra.z += rc[n] * r0.z; ra.w += rc[n] * r0.w;
        rb4.x += rc[n] * r1.x; rb4.y += rc[n] * r1.y; rb4.z += rc[n] * r1.z; rb4.w += rc[n] * r1.w;
    }
    float* Ks  = ws + (size_t)b * DIM * DIM;
    float* KsT = ws + (size_t)BATCH * DIM * DIM + (size_t)b * DIM * DIM;
    float* RsT = ws + (size_t)2 * BATCH * DIM * DIM + (size_t)b * DIM * DIM;
    *reinterpret_cast<float4*>(Ks + boff)     = ka;
    *reinterpret_cast<float4*>(Ks + boff + 4) = kb4;
    const float kv[8] = {ka.x, ka.y, ka.z, ka.w, kb4.x, kb4.y, kb4.z, kb4.w};
    const float rv[8] = {ra.x, ra.y, ra.z, ra.w, rb4.x, rb4.y, rb4.z, rb4.w};
    #pragma unroll
    for (int j = 0; j < 8; ++j) {
        KsT[(c + j) * DIM + r] = kv[j];
        RsT[(c + j) * DIM + r] = rv[j];
    }
}

// ============ whole problem: 1 block = 1 batch, MFMA chain in LDS ============
template<int PRE>
__global__ __launch_bounds__(1024) __attribute__((amdgpu_waves_per_eu(4, 4)))
void htg_mfma(const float* __restrict__ z0r, const float* __restrict__ z0i,
              const float* __restrict__ ts,  const float* __restrict__ kco,
              const float* __restrict__ rco, const float* __restrict__ alp,
              const float* __restrict__ bet, const float* __restrict__ KB,
              const float* __restrict__ RB,  const float* __restrict__ wsum,
              float* __restrict__ outF, int interleaved, int out_size)
{
    __shared__ short nm_hi[DIM * LDA], nm_lo[DIM * LDA];   // row-major planes
    __shared__ short tr_hi[DIM * LDA], tr_lo[DIM * LDA];   // transposed planes
    __shared__ short ht_hi[32 * LDA],  ht_lo[32 * LDA];    // u-table A

    const int b = blockIdx.x, t = threadIdx.x;
    const int w = t >> 6, lane = t & 63;
    const int l15 = lane & 15, quad = lane >> 4;            // 16x16 paths
    const int l31 = lane & 31, kq = lane >> 5;              // 32x32 paths
    const f4v z4 = {0.f, 0.f, 0.f, 0.f};
    const int mb = (w & 3) * 32, nb = (w >> 2) * 32;        // 4x4 grid of 32x32

    // ---- S1 ----
    if (PRE) {
        const float* RsT = wsum + (size_t)2 * BATCH * DIM * DIM + (size_t)b * DIM * DIM;
        #pragma unroll
        for (int q = 0; q < 4; ++q) {
            const int e = q * 4096 + t * 4;
            const float4 rv = *reinterpret_cast<const float4*>(RsT + e);
            const int row = e >> 7, colr = e & 127;
            const float rr[4] = {rv.x, rv.y, rv.z, rv.w};
            s4v h4, l4;
            #pragma unroll
            for (int j = 0; j < 4; ++j) {
                short hi, lo; splitbf(rr[j], hi, lo);
                h4[j] = hi; l4[j] = lo;
            }
            st4(&tr_hi[row * LDA + colr], h4);
            st4(&tr_lo[row * LDA + colr], l4);
        }
        if (t < 2 * DIM) {
            const int c = t >> 7, o = t & 127;
            const float zv = (c == 0) ? z0r[b * DIM + o] : z0i[b * DIM + o];
            short hi, lo; splitbf(zv, hi, lo);
            ht_hi[c * LDA + o] = hi; ht_lo[c * LDA + o] = lo;
        }
    } else {
        float rc[NBASES], kc[NBASES];
        #pragma unroll
        for (int n = 0; n < NBASES; ++n) {
            rc[n] = rco[b * NBASES + n];
            kc[n] = kco[b * NBASES + n];
        }
        #pragma unroll
        for (int q = 0; q < 4; ++q) {
            const int e = q * 4096 + t * 4;
            float4 r4 = {0.f, 0.f, 0.f, 0.f}, k4 = {0.f, 0.f, 0.f, 0.f};
            #pragma unroll
            for (int n = 0; n < NBASES; ++n) {
                const float4 rvv = *reinterpret_cast<const float4*>(RB + n * DIM * DIM + e);
                const float4 kvv = *reinterpret_cast<const float4*>(KB + n * DIM * DIM + e);
                r4.x += rc[n] * rvv.x; r4.y += rc[n] * rvv.y;
                r4.z += rc[n] * rvv.z; r4.w += rc[n] * rvv.w;
                k4.x += kc[n] * kvv.x; k4.y += kc[n] * kvv.y;
                k4.z += kc[n] * kvv.z; k4.w += kc[n] * kvv.w;
            }
            const int r = e >> 7, c = e & 127;
            const float rr[4] = {r4.x, r4.y, r4.z, r4.w};
            const float kk[4] = {k4.x, k4.y, k4.z, k4.w};
            s4v kh, kl;
            #pragma unroll
            for (int j = 0; j < 4; ++j) {
                short hi, lo;
                splitbf(rr[j], hi, lo);
                tr_hi[(c + j) * LDA + r] = hi; tr_lo[(c + j) * LDA + r] = lo;
                splitbf(kk[j], hi, lo);
                kh[j] = hi; kl[j] = lo;
            }
            st4(&nm_hi[r * LDA + c], kh);
            st4(&nm_lo[r * LDA + c], kl);
        }
        if (t < 2 * DIM) {
            const int c = t >> 7, o = t & 127;
            const float zv = (c == 0) ? z0r[b * DIM + o] : z0i[b * DIM + o];
            short hi, lo; splitbf(zv, hi, lo);
            ht_hi[c * LDA + o] = hi; ht_lo[c * LDA + o] = lo;
        }
    }
    __syncthreads();

    f16v acc, acct;
    float xsave[16], xsaveT[16];   // X / X^T tiles (exact fp32)

    // ---- Op1: gram = R^T@R (dual). kd/kdT preloaded BEFORE the mm. ----
    float kd[4][4], kdT[4][4];
    if (PRE) {
        const float* Ks  = wsum + (size_t)b * DIM * DIM;
        const float* KsT = wsum + (size_t)BATCH * DIM * DIM + (size_t)b * DIM * DIM;
        #pragma unroll
        for (int r4 = 0; r4 < 4; ++r4) {
            const int row0 = mb + 8 * r4 + 4 * kq;
            const int col  = nb + l31;
            const int rt0  = nb + 8 * r4 + 4 * kq;
            const int ct   = mb + l31;
            #pragma unroll
            for (int j = 0; j < 4; ++j) {
                kd[r4][j]  = Ks[(row0 + j) * DIM + col] - KsT[(row0 + j) * DIM + col];
                kdT[r4][j] = KsT[(rt0 + j) * DIM + ct]  - Ks[(rt0 + j) * DIM + ct];
            }
        }
    } else {
        #pragma unroll
        for (int r4 = 0; r4 < 4; ++r4) {
            {
                const int row0 = mb + 8 * r4 + 4 * kq;
                const int col  = nb + l31;
                const s4v k2h = ld4(&nm_hi[col * LDA + row0]);
                const s4v k2l = ld4(&nm_lo[col * LDA + row0]);
                #pragma unroll
                for (int j = 0; j < 4; ++j)
                    kd[r4][j] = (upbf(nm_hi[(row0 + j) * LDA + col]) +
                                 upbf(nm_lo[(row0 + j) * LDA + col]))
                              - (upbf(k2h[j]) + upbf(k2l[j]));
            }
            {
                const int rt0 = nb + 8 * r4 + 4 * kq;
                const int ct  = mb + l31;
                const s4v k1h = ld4(&nm_hi[ct * LDA + rt0]);
                const s4v k1l = ld4(&nm_lo[ct * LDA + rt0]);
                #pragma unroll
                for (int j = 0; j < 4; ++j)
                    kdT[r4][j] = (upbf(k1h[j]) + upbf(k1l[j]))
                               - (upbf(nm_hi[(rt0 + j) * LDA + ct]) +
                                  upbf(nm_lo[(rt0 + j) * LDA + ct]));
            }
        }
    }
    #pragma unroll
    for (int i = 0; i < 16; ++i) { acc[i] = 0.f; acct[i] = 0.f; }
    mm32<true, true>(tr_hi, tr_lo, tr_hi, tr_lo, acc, acct, mb, nb, lane);
    __syncthreads();   // all R (and legacy K) reads done -> safe to overwrite
    {
        const float alpha = alp[b], beta = bet[b], dtf = ts[0];
        #pragma unroll
        for (int r4 = 0; r4 < 4; ++r4) {
            {   // X tile -> tr (X^T layout) + xsave
                const int row0 = mb + 8 * r4 + 4 * kq;
                const int col  = nb + l31;
                s4v h4, l4;
                #pragma unroll
                for (int j = 0; j < 4; ++j) {
                    float x = (alpha * kd[r4][j] - beta * acc[4 * r4 + j]) * dtf;
                    if (row0 + j == col) x += 1e-6f;
                    xsave[4 * r4 + j] = x;
                    short hi, lo; splitbf(x, hi, lo);
                    h4[j] = hi; l4[j] = lo;
                }
                st4(&tr_hi[col * LDA + row0], h4);
                st4(&tr_lo[col * LDA + row0], l4);
            }
            {   // X^T tile -> nm (row-major X) + xsaveT
                const int rt0 = nb + 8 * r4 + 4 * kq;
                const int ct  = mb + l31;
                s4v h4, l4;
                #pragma unroll
                for (int j = 0; j < 4; ++j) {
                    float x = (alpha * kdT[r4][j] - beta * acct[4 * r4 + j]) * dtf;
                    if (ct == rt0 + j) x += 1e-6f;
                    xsaveT[4 * r4 + j] = x;
                    short hi, lo; splitbf(x, hi, lo);
                    h4[j] = hi; l4[j] = lo;
                }
                st4(&nm_hi[ct * LDA + rt0], h4);
                st4(&nm_lo[ct * LDA + rt0], l4);
            }
        }
    }
    __syncthreads();

    // ---- Op2'': C = X@X (dual); M = I + X + C/2 (Taylor-2; truncation
    //      ~||X||^3/6 per step << chain bf16 error floor) -> nm + tr directly.
    //      Both orientations exact fp32 from xsave/xsaveT + acc/acct. ----
    #pragma unroll
    for (int i = 0; i < 16; ++i) { acc[i] = 0.f; acct[i] = 0.f; }
    mm32<true, true>(nm_hi, nm_lo, tr_hi, tr_lo, acc, acct, mb, nb, lane);
    __syncthreads();
    #pragma unroll
    for (int r4 = 0; r4 < 4; ++r4) {
        {   // M^T -> tr from normal tile
            const int row0 = mb + 8 * r4 + 4 * kq;
            const int col  = nb + l31;
            s4v h4, l4;
            #pragma unroll
            for (int j = 0; j < 4; ++j) {
                const float m = ((row0 + j == col) ? 1.f : 0.f)
                              + xsave[4 * r4 + j] + 0.5f * acc[4 * r4 + j];
                short hi, lo; splitbf(m, hi, lo);
                h4[j] = hi; l4[j] = lo;
            }
            st4(&tr_hi[col * LDA + row0], h4);        // M^T
            st4(&tr_lo[col * LDA + row0], l4);
        }
        {   // M -> nm from transposed tile
            const int rt0 = nb + 8 * r4 + 4 * kq;
            const int ct  = mb + l31;
            s4v h4, l4;
            #pragma unroll
            for (int j = 0; j < 4; ++j) {
                const float m = ((ct == rt0 + j) ? 1.f : 0.f)
                              + xsaveT[4 * r4 + j] + 0.5f * acct[4 * r4 + j];
                short hi, lo; splitbf(m, hi, lo);
                h4[j] = hi; l4[j] = lo;
            }
            st4(&nm_hi[ct * LDA + rt0], h4);          // M row-major
            st4(&nm_lo[ct * LDA + rt0], l4);
        }
    }
    __syncthreads();

    float arsave[4][4];   // deferred seed-round outputs (global stores at end)

    // ---- seed stages 0..2: FUSED {round (16x16, waves 0-7) + squaring (32x32)} ----
    #pragma unroll
    for (int stage = 0; stage < 3; ++stage) {
        const int J = 1 << stage;
        f4v ar = z4;
        #pragma unroll
        for (int i = 0; i < 16; ++i) { acc[i] = 0.f; acct[i] = 0.f; }
        if (w < 8) {
            #pragma unroll
            for (int kk = 0; kk < DIM; kk += 32) {
                const int ko = kk + quad * 8;
                const s8v rah = ld8(nm_hi + (w * 16 + l15) * LDA + ko);
                const s8v ral = ld8(nm_lo + (w * 16 + l15) * LDA + ko);
                const s8v rbh = ld8(ht_hi + l15 * LDA + ko);
                const s8v rbl = ld8(ht_lo + l15 * LDA + ko);
                ar = mf(rah, rbh, ar);
                ar = mf(rah, rbl, ar);
                ar = mf(ral, rbh, ar);
            }
        }
        mm32<true, true>(nm_hi, nm_lo, tr_hi, tr_lo, acc, acct, mb, nb, lane);
        __syncthreads();
        #pragma unroll
        for (int r = 0; r < 4; ++r) arsave[stage][r] = ar[r];
        if (w < 8 && l15 < 2 * J) {
            const int o0 = w * 16 + quad * 4;
            s4v h4, l4;
            #pragma unroll
            for (int r = 0; r < 4; ++r) {
                short hi, lo; splitbf(ar[r], hi, lo);
                h4[r] = hi; l4[r] = lo;
            }
            st4(&ht_hi[(l15 + 2 * J) * LDA + o0], h4);
            st4(&ht_lo[(l15 + 2 * J) * LDA + o0], l4);
        }
        #pragma unroll
        for (int r4 = 0; r4 < 4; ++r4) {
            {
                const int row0 = mb + 8 * r4 + 4 * kq;
                const int col  = nb + l31;
                s4v h4, l4;
                #pragma unroll
                for (int j = 0; j < 4; ++j) {
                    short hi, lo; splitbf(acc[4 * r4 + j], hi, lo);
                    h4[j] = hi; l4[j] = lo;
                }
                st4(&tr_hi[col * LDA + row0], h4);
                st4(&tr_lo[col * LDA + row0], l4);
            }
            {
                const int rt0 = nb + 8 * r4 + 4 * kq;
                const int ct  = mb + l31;
                s4v h4, l4;
                #pragma unroll
                for (int j = 0; j < 4; ++j) {
                    short hi, lo; splitbf(acct[4 * r4 + j], hi, lo);
                    h4[j] = hi; l4[j] = lo;
                }
                st4(&nm_hi[ct * LDA + rt0], h4);
                st4(&nm_lo[ct * LDA + rt0], l4);
            }
        }
        __syncthreads();
    }

    // ---- stage 3 (J=8): round + LAST squaring (NM-only; tr dies here) ----
    {
        const int J = 8;
        f4v ar = z4;
        #pragma unroll
        for (int i = 0; i < 16; ++i) acct[i] = 0.f;
        if (w < 8) {
            #pragma unroll
            for (int kk = 0; kk < DIM; kk += 32) {
                const int ko = kk + quad * 8;
                const s8v rah = ld8(nm_hi + (w * 16 + l15) * LDA + ko);
                const s8v ral = ld8(nm_lo + (w * 16 + l15) * LDA + ko);
                const s8v rbh = ld8(ht_hi + l15 * LDA + ko);
                const s8v rbl = ld8(ht_lo + l15 * LDA + ko);
                ar = mf(rah, rbh, ar);
                ar = mf(rah, rbl, ar);
                ar = mf(ral, rbh, ar);
            }
        }
        mm32<false, true>(nm_hi, nm_lo, tr_hi, tr_lo, acc, acct, mb, nb, lane);
        __syncthreads();
        #pragma unroll
        for (int r = 0; r < 4; ++r) arsave[3][r] = ar[r];
        if (w < 8 && l15 < 2 * J) {
            const int o0 = w * 16 + quad * 4;
            s4v h4, l4;
            #pragma unroll
            for (int r = 0; r < 4; ++r) {
                short hi, lo; splitbf(ar[r], hi, lo);
                h4[r] = hi; l4[r] = lo;
            }
            st4(&ht_hi[(l15 + 2 * J) * LDA + o0], h4);
            st4(&ht_lo[(l15 + 2 * J) * LDA + o0], l4);
        }
        #pragma unroll
        for (int r4 = 0; r4 < 4; ++r4) {
            const int rt0 = nb + 8 * r4 + 4 * kq;
            const int ct  = mb + l31;
            s4v h4, l4;
            #pragma unroll
            for (int j = 0; j < 4; ++j) {
                short hi, lo; splitbf(acct[4 * r4 + j], hi, lo);
                h4[j] = hi; l4[j] = lo;
            }
            st4(&nm_hi[ct * LDA + rt0], h4);      // V = M^16
            st4(&nm_lo[ct * LDA + rt0], l4);
        }
        __syncthreads();
    }

    // ---- 8 windows: rows <- V @ rows, ping-pong htA <-> htB (htB on dead tr).
    //      One barrier per window (none after the last). Global stores DEFERRED
    //      to the end so barriers never drain vmcnt on output stores. ----
    const int sw = w >> 1, ct = w & 1;
    s8v vah[4], val[4];
    #pragma unroll
    for (int k4 = 0; k4 < 4; ++k4) {
        const int ko = k4 * 32 + quad * 8;
        vah[k4] = ld8(nm_hi + (sw * 16 + l15) * LDA + ko);
        val[k4] = ld8(nm_lo + (sw * 16 + l15) * LDA + ko);
    }
    float wout[8][4];
    short *rh_hi = ht_hi, *rh_lo = ht_lo;
    short *wh_hi = tr_hi, *wh_lo = tr_lo;
    #pragma unroll
    for (int q = 1; q <= 8; ++q) {
        f4v a2 = z4;
        #pragma unroll
        for (int k4 = 0; k4 < 4; ++k4) {
            const int ko = k4 * 32 + quad * 8;
            const s8v bh = ld8(rh_hi + (ct * 16 + l15) * LDA + ko);
            const s8v bl = ld8(rh_lo + (ct * 16 + l15) * LDA + ko);
            a2 = mf(vah[k4], bh, a2);
            a2 = mf(vah[k4], bl, a2);
            a2 = mf(val[k4], bh, a2);
        }
        #pragma unroll
        for (int r = 0; r < 4; ++r) wout[q - 1][r] = a2[r];
        if (q < 8) {
            const int o0 = sw * 16 + quad * 4;
            const int n = ct * 16 + l15;
            s4v h4, l4;
            #pragma unroll
            for (int r = 0; r < 4; ++r) {
                short hi, lo; splitbf(a2[r], hi, lo);
                h4[r] = hi; l4[r] = lo;
            }
            st4(&wh_hi[n * LDA + o0], h4);
            st4(&wh_lo[n * LDA + o0], l4);
            __syncthreads();
        }
        short* tp;
        tp = rh_hi; rh_hi = wh_hi; wh_hi = tp;
        tp = rh_lo; rh_lo = wh_lo; wh_lo = tp;
    }

    // ---- deferred global stores: seed rounds + windows ----
    #pragma unroll
    for (int stage = 0; stage < 4; ++stage) {
        const int J = 1 << stage;
        if (w < 8 && l15 < 2 * J) {
            const int o0 = w * 16 + quad * 4;
            const int sidx = (l15 >> 1) + J - 1;
            #pragma unroll
            for (int r = 0; r < 4; ++r)
                write_out(outF, b, sidx, o0 + r, l15 & 1, arsave[stage][r],
                          interleaved, out_size);
        }
    }
    {
        const int o0 = sw * 16 + quad * 4;
        const int n = ct * 16 + l15;
        #pragma unroll
        for (int q = 1; q <= 8; ++q) {
            const int sidx = 16 * q + (n >> 1) - 1;
            if (sidx < SSTEPS) {
                #pragma unroll
                for (int r = 0; r < 4; ++r)
                    write_out(outF, b, sidx, o0 + r, n & 1, wout[q - 1][r],
                              interleaved, out_size);
            }
        }
    }
}

// ================= host =================
extern "C" void kernel_launch(void* const* d_in, const int* in_sizes, int n_in,
                              void* d_out, int out_size, void* d_ws, size_t ws_size,
                              hipStream_t stream)
{
    (void)in_sizes; (void)n_in;
    const float* z0r = (const float*)d_in[0];
    const float* z0i = (const float*)d_in[1];
    const float* ts  = (const float*)d_in[2];
    const float* kco = (const float*)d_in[3];
    const float* rco = (const float*)d_in[4];
    const float* alp = (const float*)d_in[5];
    const float* bet = (const float*)d_in[6];
    const float* KB  = (const float*)d_in[7];
    const float* RB  = (const float*)d_in[8];
    float* outF = (float*)d_out;

    const int interleaved = (out_size >= 2 * BATCH * SSTEPS * DIM) ? 1 : 0;
    const size_t ws_needed = (size_t)3 * BATCH * DIM * DIM * sizeof(float);  // 6 MB

    if (d_ws != nullptr && ws_size >= ws_needed) {
        float* ws = (float*)d_ws;
        sum_kr<<<dim3(BATCH * 8), dim3(256), 0, stream>>>(kco, rco, KB, RB, ws);
        htg_mfma<1><<<dim3(BATCH), dim3(1024), 0, stream>>>(
            z0r, z0i, ts, kco, rco, alp, bet, KB, RB, ws, outF, interleaved, out_size);
    } else {
        htg_mfma<0><<<dim3(BATCH), dim3(1024), 0, stream>>>(
            z0r, z0i, ts, kco, rco, alp, bet, KB, RB, nullptr, outF, interleaved, out_size);
    }
}

// Round 10
// 112.704 us; speedup vs baseline: 1.0425x; 1.0425x over previous
//
#include <hip/hip_runtime.h>

#define BATCH   32
#define DIM     128
#define NBASES  8
#define SSTEPS  128
#define LDA     136   // padded row (shorts): 272 B stride, 16B-aligned rows

typedef __attribute__((ext_vector_type(8)))  short s8v;   // 8 bf16 (4 VGPR)
typedef __attribute__((ext_vector_type(4)))  short s4v;   // 4 bf16 (8B packed store)
typedef __attribute__((ext_vector_type(4)))  float f4v;   // 16x16 MFMA acc
typedef __attribute__((ext_vector_type(16))) float f16v;  // 32x32 MFMA acc

__device__ __forceinline__ f4v mf(s8v a, s8v b, f4v c) {
    return __builtin_amdgcn_mfma_f32_16x16x32_bf16(a, b, c, 0, 0, 0);
}
__device__ __forceinline__ f16v mf32(s8v a, s8v b, f16v c) {
    return __builtin_amdgcn_mfma_f32_32x32x16_bf16(a, b, c, 0, 0, 0);
}
__device__ __forceinline__ s8v ld8(const short* p) {
    return *reinterpret_cast<const s8v*>(p);
}
__device__ __forceinline__ s4v ld4(const short* p) {
    return *reinterpret_cast<const s4v*>(p);
}
__device__ __forceinline__ void st4(short* p, s4v v) {
    *reinterpret_cast<s4v*>(p) = v;   // 8B-aligned at all call sites -> ds_write_b64
}
__device__ __forceinline__ float upbf(short h) {
    return __uint_as_float(((unsigned)(unsigned short)h) << 16);
}
// split fp32 -> bf16 hi + bf16 lo (truncation; dropped residual ~2^-16 rel)
__device__ __forceinline__ void splitbf(float v, short& hi, short& lo) {
    const unsigned u = __float_as_uint(v);
    hi = (short)(u >> 16);
    const float fh = __uint_as_float(u & 0xffff0000u);
    lo = (short)(__float_as_uint(v - fh) >> 16);
}

__device__ __forceinline__ void write_out(float* __restrict__ outF, int b, int sidx,
                                          int o, int c, float val,
                                          int interleaved, int out_size)
{
    if (interleaved) {
        const int oi = ((b * SSTEPS + sidx) * DIM + o) * 2 + c;
        if (oi < out_size) outF[oi] = val;
    } else if (c == 0) {
        const int oi = (b * SSTEPS + sidx) * DIM + o;
        if (oi < out_size) outF[oi] = val;
    }
}

// ---- full 128x128x128 split-bf16 MFMA matmul: 16 waves, wave = one 32x32
// v_mfma_f32_32x32x16_bf16 tile. A row-major from "norm" planes, B^T from
// "trans" planes. TRO: acc = C tile. NMO: acct = C^T tile (operand swap on
// the SAME loaded fragments -> no extra LDS reads).
template<bool TRO, bool NMO>
__device__ __forceinline__ void mm32(const short* __restrict__ Ah,
                                     const short* __restrict__ Al,
                                     const short* __restrict__ Bh,
                                     const short* __restrict__ Bl,
                                     f16v& acc, f16v& acct,
                                     int mb, int nb, int lane)
{
    const int l31 = lane & 31, koc = (lane >> 5) * 8;
    #pragma unroll
    for (int ks = 0; ks < 8; ++ks) {
        const int ko = ks * 16 + koc;
        const s8v ah = ld8(Ah + (mb + l31) * LDA + ko);
        const s8v al = ld8(Al + (mb + l31) * LDA + ko);
        const s8v bh = ld8(Bh + (nb + l31) * LDA + ko);
        const s8v bl = ld8(Bl + (nb + l31) * LDA + ko);
        if (TRO) {
            acc = mf32(ah, bh, acc);
            acc = mf32(ah, bl, acc);
            acc = mf32(al, bh, acc);
        }
        if (NMO) {
            acct = mf32(bh, ah, acct);
            acct = mf32(bl, ah, acct);
            acct = mf32(bh, al, acct);
        }
    }
}

// ======== prologue: K_sum / K_sum^T / R_sum^T on 256 blocks -> d_ws ========
// ws layout (fp32): Ks[32][128][128], KsT[32][128][128], RsT[32][128][128] = 6 MB
__global__ __launch_bounds__(256)
void sum_kr(const float* __restrict__ kco, const float* __restrict__ rco,
            const float* __restrict__ KB,  const float* __restrict__ RB,
            float* __restrict__ ws)
{
    const int b = blockIdx.x >> 3, s = blockIdx.x & 7, t = threadIdx.x;
    const int boff = s * 16 * DIM + t * 8;           // row r, cols c..c+7
    const int r = s * 16 + (t >> 4), c = (t & 15) * 8;
    float kc[NBASES], rc[NBASES];
    #pragma unroll
    for (int n = 0; n < NBASES; ++n) {
        kc[n] = kco[b * NBASES + n];
        rc[n] = rco[b * NBASES + n];
    }
    float4 ka = {0.f,0.f,0.f,0.f}, kb4 = {0.f,0.f,0.f,0.f};
    float4 ra = {0.f,0.f,0.f,0.f}, rb4 = {0.f,0.f,0.f,0.f};
    #pragma unroll
    for (int n = 0; n < NBASES; ++n) {
        const float4 k0 = *reinterpret_cast<const float4*>(KB + n * DIM * DIM + boff);
        const float4 k1 = *reinterpret_cast<const float4*>(KB + n * DIM * DIM + boff + 4);
        const float4 r0 = *reinterpret_cast<const float4*>(RB + n * DIM * DIM + boff);
        const float4 r1 = *reinterpret_cast<const float4*>(RB + n * DIM * DIM + boff + 4);
        ka.x += kc[n] * k0.x; ka.y += kc[n] * k0.y; ka.z += kc[n] * k0.z; ka.w += kc[n] * k0.w;
        kb4.x += kc[n] * k1.x; kb4.y += kc[n] * k1.y; kb4.z += kc[n] * k1.z; kb4.w += kc[n] * k1.w;
        ra.x += rc[n] * r0.x; ra.y += rc[n] * r0.y; ra.z += rc[n] * r0.z; ra.w += rc[n] * r0.w;
        rb4.x += rc[n] * r1.x; rb4.y += rc[n] * r1.y; rb4.z += rc[n] * r1.z; rb4.w += rc[n] * r1.w;
    }
    float* Ks  = ws + (size_t)b * DIM * DIM;
    float* KsT = ws + (size_t)BATCH * DIM * DIM + (size_t)b * DIM * DIM;
    float* RsT = ws + (size_t)2 * BATCH * DIM * DIM + (size_t)b * DIM * DIM;
    *reinterpret_cast<float4*>(Ks + boff)     = ka;
    *reinterpret_cast<float4*>(Ks + boff + 4) = kb4;
    const float kv[8] = {ka.x, ka.y, ka.z, ka.w, kb4.x, kb4.y, kb4.z, kb4.w};
    const float rv[8] = {ra.x, ra.y, ra.z, ra.w, rb4.x, rb4.y, rb4.z, rb4.w};
    #pragma unroll
    for (int j = 0; j < 8; ++j) {
        KsT[(c + j) * DIM + r] = kv[j];
        RsT[(c + j) * DIM + r] = rv[j];
    }
}

// ============ whole problem: 1 block = 1 batch, MFMA chain in LDS ============
template<int PRE>
__global__ __launch_bounds__(1024) __attribute__((amdgpu_waves_per_eu(4, 4)))
void htg_mfma(const float* __restrict__ z0r, const float* __restrict__ z0i,
              const float* __restrict__ ts,  const float* __restrict__ kco,
              const float* __restrict__ rco, const float* __restrict__ alp,
              const float* __restrict__ bet, const float* __restrict__ KB,
              const float* __restrict__ RB,  const float* __restrict__ wsum,
              float* __restrict__ outF, int interleaved, int out_size)
{
    __shared__ short nm_hi[DIM * LDA], nm_lo[DIM * LDA];   // row-major planes
    __shared__ short tr_hi[DIM * LDA], tr_lo[DIM * LDA];   // transposed planes
    __shared__ short ht_hi[32 * LDA],  ht_lo[32 * LDA];    // u-table A

    const int b = blockIdx.x, t = threadIdx.x;
    const int w = t >> 6, lane = t & 63;
    const int l15 = lane & 15, quad = lane >> 4;            // 16x16 paths
    const int l31 = lane & 31, kq = lane >> 5;              // 32x32 paths
    const f4v z4 = {0.f, 0.f, 0.f, 0.f};
    const int mb = (w & 3) * 32, nb = (w >> 2) * 32;        // 4x4 grid of 32x32

    // ---- S1 ----
    if (PRE) {
        const float* RsT = wsum + (size_t)2 * BATCH * DIM * DIM + (size_t)b * DIM * DIM;
        #pragma unroll
        for (int q = 0; q < 4; ++q) {
            const int e = q * 4096 + t * 4;
            const float4 rv = *reinterpret_cast<const float4*>(RsT + e);
            const int row = e >> 7, colr = e & 127;
            const float rr[4] = {rv.x, rv.y, rv.z, rv.w};
            s4v h4, l4;
            #pragma unroll
            for (int j = 0; j < 4; ++j) {
                short hi, lo; splitbf(rr[j], hi, lo);
                h4[j] = hi; l4[j] = lo;
            }
            st4(&tr_hi[row * LDA + colr], h4);
            st4(&tr_lo[row * LDA + colr], l4);
        }
        if (t < 2 * DIM) {
            const int c = t >> 7, o = t & 127;
            const float zv = (c == 0) ? z0r[b * DIM + o] : z0i[b * DIM + o];
            short hi, lo; splitbf(zv, hi, lo);
            ht_hi[c * LDA + o] = hi; ht_lo[c * LDA + o] = lo;
        }
    } else {
        float rc[NBASES], kc[NBASES];
        #pragma unroll
        for (int n = 0; n < NBASES; ++n) {
            rc[n] = rco[b * NBASES + n];
            kc[n] = kco[b * NBASES + n];
        }
        #pragma unroll
        for (int q = 0; q < 4; ++q) {
            const int e = q * 4096 + t * 4;
            float4 r4 = {0.f, 0.f, 0.f, 0.f}, k4 = {0.f, 0.f, 0.f, 0.f};
            #pragma unroll
            for (int n = 0; n < NBASES; ++n) {
                const float4 rvv = *reinterpret_cast<const float4*>(RB + n * DIM * DIM + e);
                const float4 kvv = *reinterpret_cast<const float4*>(KB + n * DIM * DIM + e);
                r4.x += rc[n] * rvv.x; r4.y += rc[n] * rvv.y;
                r4.z += rc[n] * rvv.z; r4.w += rc[n] * rvv.w;
                k4.x += kc[n] * kvv.x; k4.y += kc[n] * kvv.y;
                k4.z += kc[n] * kvv.z; k4.w += kc[n] * kvv.w;
            }
            const int r = e >> 7, c = e & 127;
            const float rr[4] = {r4.x, r4.y, r4.z, r4.w};
            const float kk[4] = {k4.x, k4.y, k4.z, k4.w};
            s4v kh, kl;
            #pragma unroll
            for (int j = 0; j < 4; ++j) {
                short hi, lo;
                splitbf(rr[j], hi, lo);
                tr_hi[(c + j) * LDA + r] = hi; tr_lo[(c + j) * LDA + r] = lo;
                splitbf(kk[j], hi, lo);
                kh[j] = hi; kl[j] = lo;
            }
            st4(&nm_hi[r * LDA + c], kh);
            st4(&nm_lo[r * LDA + c], kl);
        }
        if (t < 2 * DIM) {
            const int c = t >> 7, o = t & 127;
            const float zv = (c == 0) ? z0r[b * DIM + o] : z0i[b * DIM + o];
            short hi, lo; splitbf(zv, hi, lo);
            ht_hi[c * LDA + o] = hi; ht_lo[c * LDA + o] = lo;
        }
    }
    __syncthreads();

    f16v acc, acct;
    float xsave[16], xsaveT[16];   // X / X^T tiles (exact fp32)

    // ---- Op1: gram = R^T@R (dual). kd/kdT preloaded BEFORE the mm. ----
    float kd[4][4], kdT[4][4];
    if (PRE) {
        const float* Ks  = wsum + (size_t)b * DIM * DIM;
        const float* KsT = wsum + (size_t)BATCH * DIM * DIM + (size_t)b * DIM * DIM;
        #pragma unroll
        for (int r4 = 0; r4 < 4; ++r4) {
            const int row0 = mb + 8 * r4 + 4 * kq;
            const int col  = nb + l31;
            const int rt0  = nb + 8 * r4 + 4 * kq;
            const int ct   = mb + l31;
            #pragma unroll
            for (int j = 0; j < 4; ++j) {
                kd[r4][j]  = Ks[(row0 + j) * DIM + col] - KsT[(row0 + j) * DIM + col];
                kdT[r4][j] = KsT[(rt0 + j) * DIM + ct]  - Ks[(rt0 + j) * DIM + ct];
            }
        }
    } else {
        #pragma unroll
        for (int r4 = 0; r4 < 4; ++r4) {
            {
                const int row0 = mb + 8 * r4 + 4 * kq;
                const int col  = nb + l31;
                const s4v k2h = ld4(&nm_hi[col * LDA + row0]);
                const s4v k2l = ld4(&nm_lo[col * LDA + row0]);
                #pragma unroll
                for (int j = 0; j < 4; ++j)
                    kd[r4][j] = (upbf(nm_hi[(row0 + j) * LDA + col]) +
                                 upbf(nm_lo[(row0 + j) * LDA + col]))
                              - (upbf(k2h[j]) + upbf(k2l[j]));
            }
            {
                const int rt0 = nb + 8 * r4 + 4 * kq;
                const int ct  = mb + l31;
                const s4v k1h = ld4(&nm_hi[ct * LDA + rt0]);
                const s4v k1l = ld4(&nm_lo[ct * LDA + rt0]);
                #pragma unroll
                for (int j = 0; j < 4; ++j)
                    kdT[r4][j] = (upbf(k1h[j]) + upbf(k1l[j]))
                               - (upbf(nm_hi[(rt0 + j) * LDA + ct]) +
                                  upbf(nm_lo[(rt0 + j) * LDA + ct]));
            }
        }
    }
    #pragma unroll
    for (int i = 0; i < 16; ++i) { acc[i] = 0.f; acct[i] = 0.f; }
    mm32<true, true>(tr_hi, tr_lo, tr_hi, tr_lo, acc, acct, mb, nb, lane);
    __syncthreads();   // all R (and legacy K) reads done -> safe to overwrite
    {
        const float alpha = alp[b], beta = bet[b], dtf = ts[0];
        #pragma unroll
        for (int r4 = 0; r4 < 4; ++r4) {
            {   // X tile -> tr (X^T layout) + xsave
                const int row0 = mb + 8 * r4 + 4 * kq;
                const int col  = nb + l31;
                s4v h4, l4;
                #pragma unroll
                for (int j = 0; j < 4; ++j) {
                    float x = (alpha * kd[r4][j] - beta * acc[4 * r4 + j]) * dtf;
                    if (row0 + j == col) x += 1e-6f;
                    xsave[4 * r4 + j] = x;
                    short hi, lo; splitbf(x, hi, lo);
                    h4[j] = hi; l4[j] = lo;
                }
                st4(&tr_hi[col * LDA + row0], h4);
                st4(&tr_lo[col * LDA + row0], l4);
            }
            {   // X^T tile -> nm (row-major X) + xsaveT
                const int rt0 = nb + 8 * r4 + 4 * kq;
                const int ct  = mb + l31;
                s4v h4, l4;
                #pragma unroll
                for (int j = 0; j < 4; ++j) {
                    float x = (alpha * kdT[r4][j] - beta * acct[4 * r4 + j]) * dtf;
                    if (ct == rt0 + j) x += 1e-6f;
                    xsaveT[4 * r4 + j] = x;
                    short hi, lo; splitbf(x, hi, lo);
                    h4[j] = hi; l4[j] = lo;
                }
                st4(&nm_hi[ct * LDA + rt0], h4);
                st4(&nm_lo[ct * LDA + rt0], l4);
            }
        }
    }
    __syncthreads();

    // ---- Op2'': C = X@X (dual); M = I + X + C/2 (Taylor-2; truncation
    //      ~||X||^3/6 per step << chain bf16 error floor) -> nm + tr directly. ----
    #pragma unroll
    for (int i = 0; i < 16; ++i) { acc[i] = 0.f; acct[i] = 0.f; }
    mm32<true, true>(nm_hi, nm_lo, tr_hi, tr_lo, acc, acct, mb, nb, lane);
    __syncthreads();
    #pragma unroll
    for (int r4 = 0; r4 < 4; ++r4) {
        {   // M^T -> tr from normal tile
            const int row0 = mb + 8 * r4 + 4 * kq;
            const int col  = nb + l31;
            s4v h4, l4;
            #pragma unroll
            for (int j = 0; j < 4; ++j) {
                const float m = ((row0 + j == col) ? 1.f : 0.f)
                              + xsave[4 * r4 + j] + 0.5f * acc[4 * r4 + j];
                short hi, lo; splitbf(m, hi, lo);
                h4[j] = hi; l4[j] = lo;
            }
            st4(&tr_hi[col * LDA + row0], h4);        // M^T
            st4(&tr_lo[col * LDA + row0], l4);
        }
        {   // M -> nm from transposed tile
            const int rt0 = nb + 8 * r4 + 4 * kq;
            const int ct  = mb + l31;
            s4v h4, l4;
            #pragma unroll
            for (int j = 0; j < 4; ++j) {
                const float m = ((ct == rt0 + j) ? 1.f : 0.f)
                              + xsaveT[4 * r4 + j] + 0.5f * acct[4 * r4 + j];
                short hi, lo; splitbf(m, hi, lo);
                h4[j] = hi; l4[j] = lo;
            }
            st4(&nm_hi[ct * LDA + rt0], h4);          // M row-major
            st4(&nm_lo[ct * LDA + rt0], l4);
        }
    }
    __syncthreads();

    float arp[4];   // rolling previous-round output (flushed one phase later)

    // ---- seed stages 0..2: FUSED {round (16x16, waves 0-7) + squaring (32x32)}.
    //      Previous stage's round output is flushed to global at the TOP of the
    //      next stage (right after its barrier) so stores retire under MFMA. ----
    #pragma unroll
    for (int stage = 0; stage < 3; ++stage) {
        const int J = 1 << stage;
        if (stage > 0) {
            const int Jp = J >> 1;
            if (w < 8 && l15 < 2 * Jp) {
                const int o0 = w * 16 + quad * 4;
                const int sidx = (l15 >> 1) + Jp - 1;
                #pragma unroll
                for (int r = 0; r < 4; ++r)
                    write_out(outF, b, sidx, o0 + r, l15 & 1, arp[r],
                              interleaved, out_size);
            }
        }
        f4v ar = z4;
        #pragma unroll
        for (int i = 0; i < 16; ++i) { acc[i] = 0.f; acct[i] = 0.f; }
        if (w < 8) {
            #pragma unroll
            for (int kk = 0; kk < DIM; kk += 32) {
                const int ko = kk + quad * 8;
                const s8v rah = ld8(nm_hi + (w * 16 + l15) * LDA + ko);
                const s8v ral = ld8(nm_lo + (w * 16 + l15) * LDA + ko);
                const s8v rbh = ld8(ht_hi + l15 * LDA + ko);
                const s8v rbl = ld8(ht_lo + l15 * LDA + ko);
                ar = mf(rah, rbh, ar);
                ar = mf(rah, rbl, ar);
                ar = mf(ral, rbh, ar);
            }
        }
        mm32<true, true>(nm_hi, nm_lo, tr_hi, tr_lo, acc, acct, mb, nb, lane);
        __syncthreads();
        if (w < 8 && l15 < 2 * J) {
            const int o0 = w * 16 + quad * 4;
            s4v h4, l4;
            #pragma unroll
            for (int r = 0; r < 4; ++r) {
                short hi, lo; splitbf(ar[r], hi, lo);
                h4[r] = hi; l4[r] = lo;
            }
            st4(&ht_hi[(l15 + 2 * J) * LDA + o0], h4);
            st4(&ht_lo[(l15 + 2 * J) * LDA + o0], l4);
        }
        #pragma unroll
        for (int r = 0; r < 4; ++r) arp[r] = ar[r];
        #pragma unroll
        for (int r4 = 0; r4 < 4; ++r4) {
            {
                const int row0 = mb + 8 * r4 + 4 * kq;
                const int col  = nb + l31;
                s4v h4, l4;
                #pragma unroll
                for (int j = 0; j < 4; ++j) {
                    short hi, lo; splitbf(acc[4 * r4 + j], hi, lo);
                    h4[j] = hi; l4[j] = lo;
                }
                st4(&tr_hi[col * LDA + row0], h4);
                st4(&tr_lo[col * LDA + row0], l4);
            }
            {
                const int rt0 = nb + 8 * r4 + 4 * kq;
                const int ct  = mb + l31;
                s4v h4, l4;
                #pragma unroll
                for (int j = 0; j < 4; ++j) {
                    short hi, lo; splitbf(acct[4 * r4 + j], hi, lo);
                    h4[j] = hi; l4[j] = lo;
                }
                st4(&nm_hi[ct * LDA + rt0], h4);
                st4(&nm_lo[ct * LDA + rt0], l4);
            }
        }
        __syncthreads();
    }

    // ---- stage 3 (J=8): round + LAST squaring (NM-only; tr dies here).
    //      Flush stage-2 round output at the top. ----
    {
        const int J = 8;
        {
            const int Jp = 4;
            if (w < 8 && l15 < 2 * Jp) {
                const int o0 = w * 16 + quad * 4;
                const int sidx = (l15 >> 1) + Jp - 1;
                #pragma unroll
                for (int r = 0; r < 4; ++r)
                    write_out(outF, b, sidx, o0 + r, l15 & 1, arp[r],
                              interleaved, out_size);
            }
        }
        f4v ar = z4;
        #pragma unroll
        for (int i = 0; i < 16; ++i) acct[i] = 0.f;
        if (w < 8) {
            #pragma unroll
            for (int kk = 0; kk < DIM; kk += 32) {
                const int ko = kk + quad * 8;
                const s8v rah = ld8(nm_hi + (w * 16 + l15) * LDA + ko);
                const s8v ral = ld8(nm_lo + (w * 16 + l15) * LDA + ko);
                const s8v rbh = ld8(ht_hi + l15 * LDA + ko);
                const s8v rbl = ld8(ht_lo + l15 * LDA + ko);
                ar = mf(rah, rbh, ar);
                ar = mf(rah, rbl, ar);
                ar = mf(ral, rbh, ar);
            }
        }
        mm32<false, true>(nm_hi, nm_lo, tr_hi, tr_lo, acc, acct, mb, nb, lane);
        __syncthreads();
        if (w < 8 && l15 < 2 * J) {
            const int o0 = w * 16 + quad * 4;
            s4v h4, l4;
            #pragma unroll
            for (int r = 0; r < 4; ++r) {
                short hi, lo; splitbf(ar[r], hi, lo);
                h4[r] = hi; l4[r] = lo;
            }
            st4(&ht_hi[(l15 + 2 * J) * LDA + o0], h4);
            st4(&ht_lo[(l15 + 2 * J) * LDA + o0], l4);
        }
        #pragma unroll
        for (int r = 0; r < 4; ++r) arp[r] = ar[r];
        #pragma unroll
        for (int r4 = 0; r4 < 4; ++r4) {
            const int rt0 = nb + 8 * r4 + 4 * kq;
            const int ct  = mb + l31;
            s4v h4, l4;
            #pragma unroll
            for (int j = 0; j < 4; ++j) {
                short hi, lo; splitbf(acct[4 * r4 + j], hi, lo);
                h4[j] = hi; l4[j] = lo;
            }
            st4(&nm_hi[ct * LDA + rt0], h4);      // V = M^16
            st4(&nm_lo[ct * LDA + rt0], l4);
        }
        __syncthreads();
    }

    // ---- flush stage-3 round output (overlaps window-1 compute) ----
    {
        const int Jp = 8;
        if (w < 8 && l15 < 2 * Jp) {
            const int o0 = w * 16 + quad * 4;
            const int sidx = (l15 >> 1) + Jp - 1;
            #pragma unroll
            for (int r = 0; r < 4; ++r)
                write_out(outF, b, sidx, o0 + r, l15 & 1, arp[r],
                          interleaved, out_size);
        }
    }

    // ---- 8 windows: rows <- V @ rows, ping-pong htA <-> htB (htB on dead tr).
    //      One barrier per window (none after the last). Window q's global
    //      stores issue at the top of window q+1 (rolling one-phase deferral). ----
    const int sw = w >> 1, ct = w & 1;
    s8v vah[4], val[4];
    #pragma unroll
    for (int k4 = 0; k4 < 4; ++k4) {
        const int ko = k4 * 32 + quad * 8;
        vah[k4] = ld8(nm_hi + (sw * 16 + l15) * LDA + ko);
        val[k4] = ld8(nm_lo + (sw * 16 + l15) * LDA + ko);
    }
    float wprev[4];
    short *rh_hi = ht_hi, *rh_lo = ht_lo;
    short *wh_hi = tr_hi, *wh_lo = tr_lo;
    #pragma unroll
    for (int q = 1; q <= 8; ++q) {
        if (q > 1) {   // flush window q-1 (stores retire under this window's MFMA)
            const int o0 = sw * 16 + quad * 4;
            const int n = ct * 16 + l15;
            const int sidx = 16 * (q - 1) + (n >> 1) - 1;
            if (sidx < SSTEPS) {
                #pragma unroll
                for (int r = 0; r < 4; ++r)
                    write_out(outF, b, sidx, o0 + r, n & 1, wprev[r],
                              interleaved, out_size);
            }
        }
        f4v a2 = z4;
        #pragma unroll
        for (int k4 = 0; k4 < 4; ++k4) {
            const int ko = k4 * 32 + quad * 8;
            const s8v bh = ld8(rh_hi + (ct * 16 + l15) * LDA + ko);
            const s8v bl = ld8(rh_lo + (ct * 16 + l15) * LDA + ko);
            a2 = mf(vah[k4], bh, a2);
            a2 = mf(vah[k4], bl, a2);
            a2 = mf(val[k4], bh, a2);
        }
        #pragma unroll
        for (int r = 0; r < 4; ++r) wprev[r] = a2[r];
        if (q < 8) {
            const int o0 = sw * 16 + quad * 4;
            const int n = ct * 16 + l15;
            s4v h4, l4;
            #pragma unroll
            for (int r = 0; r < 4; ++r) {
                short hi, lo; splitbf(a2[r], hi, lo);
                h4[r] = hi; l4[r] = lo;
            }
            st4(&wh_hi[n * LDA + o0], h4);
            st4(&wh_lo[n * LDA + o0], l4);
            __syncthreads();
        }
        short* tp;
        tp = rh_hi; rh_hi = wh_hi; wh_hi = tp;
        tp = rh_lo; rh_lo = wh_lo; wh_lo = tp;
    }
    // final flush: window 8 (only n<2 maps to sidx=127)
    {
        const int o0 = sw * 16 + quad * 4;
        const int n = ct * 16 + l15;
        const int sidx = 128 + (n >> 1) - 1;
        if (sidx < SSTEPS) {
            #pragma unroll
            for (int r = 0; r < 4; ++r)
                write_out(outF, b, sidx, o0 + r, n & 1, wprev[r],
                          interleaved, out_size);
        }
    }
}

// ================= host =================
extern "C" void kernel_launch(void* const* d_in, const int* in_sizes, int n_in,
                              void* d_out, int out_size, void* d_ws, size_t ws_size,
                              hipStream_t stream)
{
    (void)in_sizes; (void)n_in;
    const float* z0r = (const float*)d_in[0];
    const float* z0i = (const float*)d_in[1];
    const float* ts  = (const float*)d_in[2];
    const float* kco = (const float*)d_in[3];
    const float* rco = (const float*)d_in[4];
    const float* alp = (const float*)d_in[5];
    const float* bet = (const float*)d_in[6];
    const float* KB  = (const float*)d_in[7];
    const float* RB  = (const float*)d_in[8];
    float* outF = (float*)d_out;

    const int interleaved = (out_size >= 2 * BATCH * SSTEPS * DIM) ? 1 : 0;
    const size_t ws_needed = (size_t)3 * BATCH * DIM * DIM * sizeof(float);  // 6 MB

    if (d_ws != nullptr && ws_size >= ws_needed) {
        float* ws = (float*)d_ws;
        sum_kr<<<dim3(BATCH * 8), dim3(256), 0, stream>>>(kco, rco, KB, RB, ws);
        htg_mfma<1><<<dim3(BATCH), dim3(1024), 0, stream>>>(
            z0r, z0i, ts, kco, rco, alp, bet, KB, RB, ws, outF, interleaved, out_size);
    } else {
        htg_mfma<0><<<dim3(BATCH), dim3(1024), 0, stream>>>(
            z0r, z0i, ts, kco, rco, alp, bet, KB, RB, nullptr, outF, interleaved, out_size);
    }
}